// Round 1
// baseline (137.929 us; speedup 1.0000x reference)
//
#include <hip/hip_runtime.h>

// GridInterpolator: trilinear interpolation over 8 voxel grids.
// vox: [8, 96, 96, 96, 16] f32, gidx: [N,1] i32, pts: [N,3] f32 -> out: [N,16] f32
//
// Layout: 16 lanes per point (one lane per feature). Each corner gather is a
// 64-B contiguous segment across the 16 lanes; output store is 64-B contiguous.

#define GDIM 96
#define NFEAT 16

__global__ __launch_bounds__(256) void grid_interp_kernel(
    const float* __restrict__ vox,
    const int*   __restrict__ gidx,
    const float* __restrict__ pts,
    float*       __restrict__ out,
    int n_total)                     // N * 16
{
    const int stride = gridDim.x * blockDim.x;
    for (int tid = blockIdx.x * blockDim.x + threadIdx.x; tid < n_total; tid += stride) {
        const int p = tid >> 4;      // point index
        const int f = tid & 15;      // feature index

        // 16 lanes of a point read the same addresses -> broadcast in L1
        const float px = pts[p * 3 + 0];
        const float py = pts[p * 3 + 1];
        const float pz = pts[p * 3 + 2];
        const int   gi = gidx[p];

        // remap [-1,1] -> [0,1]
        const float ux = (px + 1.0f) * 0.5f;
        const float uy = (py + 1.0f) * 0.5f;
        const float uz = (pz + 1.0f) * 0.5f;
        const bool inside = (ux >= 0.0f) & (ux <= 1.0f) &
                            (uy >= 0.0f) & (uy <= 1.0f) &
                            (uz >= 0.0f) & (uz <= 1.0f);

        // scaled coords, truncation to base (matches astype(int32) for p>=0)
        const float sx = ux * (float)(GDIM - 1);
        const float sy = uy * (float)(GDIM - 1);
        const float sz = uz * (float)(GDIM - 1);
        const int bx = (int)sx, by = (int)sy, bz = (int)sz;
        const float fx = sx - (float)bx;
        const float fy = sy - (float)by;
        const float fz = sz - (float)bz;

        const int gbase = gi * (GDIM * GDIM * GDIM);

        float acc = 0.0f;
#pragma unroll
        for (int k = 0; k < 8; ++k) {
            // bit i of k toggles dim i; dim0=x (stride G*G), dim1=y (stride G), dim2=z (stride 1)
            const int ox = (k >> 0) & 1;
            const int oy = (k >> 1) & 1;
            const int oz = (k >> 2) & 1;
            int cx = bx + ox; cx = cx < 0 ? 0 : (cx > GDIM - 1 ? GDIM - 1 : cx);
            int cy = by + oy; cy = cy < 0 ? 0 : (cy > GDIM - 1 ? GDIM - 1 : cy);
            int cz = bz + oz; cz = cz < 0 ? 0 : (cz > GDIM - 1 ? GDIM - 1 : cz);
            const int vidx = ((gbase + cx * (GDIM * GDIM) + cy * GDIM + cz) << 4) + f;
            const float w = (ox ? fx : 1.0f - fx) *
                            (oy ? fy : 1.0f - fy) *
                            (oz ? fz : 1.0f - fz);
            acc = fmaf(vox[vidx], w, acc);
        }

        out[tid] = inside ? acc : 0.0f;
    }
}

extern "C" void kernel_launch(void* const* d_in, const int* in_sizes, int n_in,
                              void* d_out, int out_size, void* d_ws, size_t ws_size,
                              hipStream_t stream) {
    const float* vox  = (const float*)d_in[0];
    const int*   gidx = (const int*)  d_in[1];
    const float* pts  = (const float*)d_in[2];
    float*       outp = (float*)d_out;

    const int n_pts   = in_sizes[1];      // N (grid_indexes flat count)
    const int n_total = n_pts * NFEAT;    // N * 16 output elements

    const int threads = 256;
    const int blocks  = 8192;             // grid-stride; 8 elems/thread at N=1M

    grid_interp_kernel<<<blocks, threads, 0, stream>>>(vox, gidx, pts, outp, n_total);
}